// Round 8
// baseline (257.628 us; speedup 1.0000x reference)
//
#include <hip/hip_runtime.h>
#include <math.h>

typedef __fp16   fp16x2  __attribute__((ext_vector_type(2)));
typedef _Float16 half8   __attribute__((ext_vector_type(8)));
typedef float    floatx4 __attribute__((ext_vector_type(4)));

#define M_TOTAL 16384
#define K_DIM   2048
#define BM      32
#define NT      256
#define NCHUNK  64

// Pre-convert W (router||noise, fp32 [128][2048]) into ws as hi/lo f16,
// granule-major per 32-k chunk: chunk c = 8192 halves:
//   hi: [(g*128 + col)*8 + j]  (g=0..3 k-granule, col=0..127, j=0..7)
//   lo: same at +4096 halves
__global__ __launch_bounds__(256) void conv_w_kernel(
    const float* __restrict__ rw, const float* __restrict__ nw,
    _Float16* __restrict__ wsB)
{
    const int u   = blockIdx.x * 256 + threadIdx.x;  // 0..32767
    const int col = u & 127;
    const int g   = (u >> 7) & 3;
    const int c   = u >> 9;
    const float* srcRow = (col < 64) ? (rw + (size_t)col * K_DIM)
                                     : (nw + (size_t)(col - 64) * K_DIM);
    const float* src = srcRow + c * 32 + g * 8;
    const float4 v0 = *(const float4*)src;
    const float4 v1 = *(const float4*)(src + 4);
    union { fp16x2 h[4]; uint4 q; } ph, pl;
    ph.h[0] = __builtin_amdgcn_cvt_pkrtz(v0.x, v0.y);
    ph.h[1] = __builtin_amdgcn_cvt_pkrtz(v0.z, v0.w);
    ph.h[2] = __builtin_amdgcn_cvt_pkrtz(v1.x, v1.y);
    ph.h[3] = __builtin_amdgcn_cvt_pkrtz(v1.z, v1.w);
    pl.h[0] = __builtin_amdgcn_cvt_pkrtz((v0.x - (float)ph.h[0].x) * 2048.0f,
                                         (v0.y - (float)ph.h[0].y) * 2048.0f);
    pl.h[1] = __builtin_amdgcn_cvt_pkrtz((v0.z - (float)ph.h[1].x) * 2048.0f,
                                         (v0.w - (float)ph.h[1].y) * 2048.0f);
    pl.h[2] = __builtin_amdgcn_cvt_pkrtz((v1.x - (float)ph.h[2].x) * 2048.0f,
                                         (v1.y - (float)ph.h[2].y) * 2048.0f);
    pl.h[3] = __builtin_amdgcn_cvt_pkrtz((v1.z - (float)ph.h[3].x) * 2048.0f,
                                         (v1.w - (float)ph.h[3].y) * 2048.0f);
    const size_t base = (size_t)c * 8192 + ((size_t)g * 128 + col) * 8;
    *(uint4*)&wsB[base]        = ph.q;
    *(uint4*)&wsB[base + 4096] = pl.q;
}

// in-register fp32x8 -> hi/lo f16x8 split (path proven correct in r1/r7)
__device__ __forceinline__ void cvt8(const float4 v0, const float4 v1,
                                     half8& hi, half8& lo) {
    union { fp16x2 h[4]; half8 v; } H, L;
    H.h[0] = __builtin_amdgcn_cvt_pkrtz(v0.x, v0.y);
    H.h[1] = __builtin_amdgcn_cvt_pkrtz(v0.z, v0.w);
    H.h[2] = __builtin_amdgcn_cvt_pkrtz(v1.x, v1.y);
    H.h[3] = __builtin_amdgcn_cvt_pkrtz(v1.z, v1.w);
    L.h[0] = __builtin_amdgcn_cvt_pkrtz((v0.x - (float)H.h[0].x) * 2048.0f,
                                        (v0.y - (float)H.h[0].y) * 2048.0f);
    L.h[1] = __builtin_amdgcn_cvt_pkrtz((v0.z - (float)H.h[1].x) * 2048.0f,
                                        (v0.w - (float)H.h[1].y) * 2048.0f);
    L.h[2] = __builtin_amdgcn_cvt_pkrtz((v1.x - (float)H.h[2].x) * 2048.0f,
                                        (v1.y - (float)H.h[2].y) * 2048.0f);
    L.h[3] = __builtin_amdgcn_cvt_pkrtz((v1.z - (float)H.h[3].x) * 2048.0f,
                                        (v1.w - (float)H.h[3].y) * 2048.0f);
    hi = H.v; lo = L.v;
}

struct Frag {
    float4 a[4];          // A rows: [mi*2+h], mi in {0,1} (rows +0/+16), h 16B halves
    half8  bh[2], bl[2];  // B cols nt0+ni*16, hi & lo
};

__device__ __forceinline__ void loadFrag(Frag& f,
    const float* pax0, const float* pax1, const _Float16* pb, int c)
{
    const float* pa0 = pax0 + c * 32;
    const float* pa1 = pax1 + c * 32;
    f.a[0] = *(const float4*)(pa0);
    f.a[1] = *(const float4*)(pa0 + 4);
    f.a[2] = *(const float4*)(pa1);
    f.a[3] = *(const float4*)(pa1 + 4);
    const _Float16* pbc = pb + (size_t)c * 8192;
    f.bh[0] = *(const half8*)(pbc);
    f.bh[1] = *(const half8*)(pbc + 128);
    f.bl[0] = *(const half8*)(pbc + 4096);
    f.bl[1] = *(const half8*)(pbc + 4096 + 128);
}

__device__ __forceinline__ void computeFrag(const Frag& f,
    floatx4 (&acch)[2][2], floatx4 (&accx)[2][2])
{
    half8 ah[2], al[2];
    cvt8(f.a[0], f.a[1], ah[0], al[0]);
    cvt8(f.a[2], f.a[3], ah[1], al[1]);
    __builtin_amdgcn_s_setprio(1);
    #pragma unroll
    for (int mi = 0; mi < 2; ++mi)
        #pragma unroll
        for (int ni = 0; ni < 2; ++ni) {
            acch[mi][ni] = __builtin_amdgcn_mfma_f32_16x16x32_f16(ah[mi], f.bh[ni], acch[mi][ni], 0, 0, 0);
            accx[mi][ni] = __builtin_amdgcn_mfma_f32_16x16x32_f16(ah[mi], f.bl[ni], accx[mi][ni], 0, 0, 0);
            accx[mi][ni] = __builtin_amdgcn_mfma_f32_16x16x32_f16(al[mi], f.bh[ni], accx[mi][ni], 0, 0, 0);
        }
    __builtin_amdgcn_s_setprio(0);
}

// Zero-LDS, zero-barrier GEMM with a TRUE 3-set software pipeline:
// named fragment sets rotate (no register copies, so no end-of-iteration
// vmcnt(0) drain); every load has a uniform ~2-compute-body issue-to-use
// distance. Each wave owns 32 rows x 32 cols; 4 waves/block cover 128 cols.
__global__ __launch_bounds__(NT, 2) void gemm_router_kernel(
    const float* __restrict__ x,
    const _Float16* __restrict__ wsB,
    const float* __restrict__ router_b,
    const float* __restrict__ noise_b,
    const float* __restrict__ noise_u,
    float* __restrict__ out)
{
    __shared__ __align__(16) struct {
        float Cs[32][132]; float p1[32]; float p2[32]; int i1[32]; int i2[32];
    } sme;

    const int t    = threadIdx.x;
    const int lane = t & 63;
    const int w    = t >> 6;
    const int rowBase = blockIdx.x * BM;

    const int lr  = lane & 15;
    const int lg4 = lane >> 4;
    const int nt0 = w * 32;

    // per-lane fragment bases (same index algebra as r7, verified)
    const float* pax0 = x + (size_t)(rowBase + lr) * K_DIM + lg4 * 8;
    const float* pax1 = pax0 + 16 * K_DIM;
    const _Float16* pb = wsB + ((size_t)lg4 * 128 + nt0 + lr) * 8;

    floatx4 acch[2][2], accx[2][2];
    #pragma unroll
    for (int mi = 0; mi < 2; ++mi)
        #pragma unroll
        for (int ni = 0; ni < 2; ++ni) {
            acch[mi][ni] = (floatx4)0.0f;
            accx[mi][ni] = (floatx4)0.0f;
        }

    Frag s0, s1, s2;
    loadFrag(s0, pax0, pax1, pb, 0);
    loadFrag(s1, pax0, pax1, pb, 1);

    // 63 chunks in the rotating loop (21 iterations), chunk 63 in the tail.
    #pragma unroll 1
    for (int c = 0; c < NCHUNK - 1; c += 3) {
        loadFrag(s2, pax0, pax1, pb, c + 2);
        computeFrag(s0, acch, accx);
        loadFrag(s0, pax0, pax1, pb, c + 3);           // c<=60 -> c+3<=63
        computeFrag(s1, acch, accx);
        loadFrag(s1, pax0, pax1, pb, (c + 4 < NCHUNK) ? c + 4 : NCHUNK - 1);
        computeFrag(s2, acch, accx);
    }
    computeFrag(s0, acch, accx);   // chunk 63

    // ---- fused epilogue (verified in r7) ----
    #pragma unroll
    for (int mi = 0; mi < 2; ++mi)
        #pragma unroll
        for (int ni = 0; ni < 2; ++ni) {
            const floatx4 v = acch[mi][ni] + accx[mi][ni] * (1.0f / 2048.0f);
            const int col = nt0 + ni * 16 + lr;
            #pragma unroll
            for (int reg = 0; reg < 4; ++reg)
                sme.Cs[mi * 16 + lg4 * 4 + reg][col] = v[reg];
        }
    __syncthreads();

    // per-row top-2: 8 threads/row, 8 experts each, shuffle merge
    {
        const int sr = t >> 3;          // row 0..31
        const int eg = (t & 7) * 8;     // expert base
        const int grow = rowBase + sr;
        const float* urow = noise_u + (size_t)grow * 64 + eg;
        const float4 u0 = *(const float4*)urow;
        const float4 u1 = *(const float4*)(urow + 4);
        const float uu[8] = {u0.x, u0.y, u0.z, u0.w, u1.x, u1.y, u1.z, u1.w};
        float v1 = -3.0e38f, v2 = -3.0e38f;
        int i1 = 0, i2 = 0;
        #pragma unroll
        for (int j = 0; j < 8; ++j) {
            const int e = eg + j;
            const float lg = sme.Cs[sr][e] + router_b[e];
            const float nz = sme.Cs[sr][64 + e] + noise_b[e];
            const float sp = fmaxf(nz, 0.0f) + log1pf(expf(-fabsf(nz)));
            const float nv = lg + sp * uu[j];
            if (nv > v1)      { v2 = v1; i2 = i1; v1 = nv; i1 = e; }
            else if (nv > v2) { v2 = nv; i2 = e; }
        }
        #pragma unroll
        for (int m = 1; m < 8; m <<= 1) {
            const float ov1 = __shfl_xor(v1, m, 64);
            const int   oi1 = __shfl_xor(i1, m, 64);
            const float ov2 = __shfl_xor(v2, m, 64);
            const int   oi2 = __shfl_xor(i2, m, 64);
            const bool takeO = (ov1 > v1) || (ov1 == v1 && oi1 < i1);
            const float t1v = takeO ? ov1 : v1;  const int t1i = takeO ? oi1 : i1;
            const float c2v = takeO ? v1 : ov1;  const int c2i = takeO ? i1 : oi1;
            const float c3v = takeO ? ov2 : v2;  const int c3i = takeO ? oi2 : i2;
            const bool k2 = (c3v > c2v) || (c3v == c2v && c3i < c2i);
            v1 = t1v; i1 = t1i;
            v2 = k2 ? c3v : c2v; i2 = k2 ? c3i : c2i;
        }
        if ((t & 7) == 0) {
            const float e2 = expf(v2 - v1);
            const float dn = 1.0f + e2;   // other 62 slots: exp(-1e30 - m) == 0
            sme.p1[sr] = 1.0f / dn;
            sme.p2[sr] = e2 / dn;
            sme.i1[sr] = i1;
            sme.i2[sr] = i2;
            float2 idx2;
            idx2.x = (float)i1;
            idx2.y = (float)i2;
            *(float2*)&out[(size_t)M_TOTAL * 64 + (size_t)grow * 2] = idx2;
        }
    }
    __syncthreads();

    // cooperative sparse-softmax write: 32 rows x 64 experts, 8 floats/thread
    {
        const int rr = t >> 3;
        const int e0 = (t & 7) * 8;
        const int g2 = rowBase + rr;
        const int j1 = sme.i1[rr], j2 = sme.i2[rr];
        const float q1 = sme.p1[rr], q2 = sme.p2[rr];
        float* orow = out + (size_t)g2 * 64;
        #pragma unroll
        for (int g = 0; g < 2; ++g) {
            const int b0 = e0 + g * 4;
            float4 v;
            v.x = (b0 + 0 == j1) ? q1 : (b0 + 0 == j2) ? q2 : 0.0f;
            v.y = (b0 + 1 == j1) ? q1 : (b0 + 1 == j2) ? q2 : 0.0f;
            v.z = (b0 + 2 == j1) ? q1 : (b0 + 2 == j2) ? q2 : 0.0f;
            v.w = (b0 + 3 == j1) ? q1 : (b0 + 3 == j2) ? q2 : 0.0f;
            *(float4*)&orow[b0] = v;
        }
    }
}

extern "C" void kernel_launch(void* const* d_in, const int* in_sizes, int n_in,
                              void* d_out, int out_size, void* d_ws, size_t ws_size,
                              hipStream_t stream) {
    const float* x  = (const float*)d_in[0];
    const float* rw = (const float*)d_in[1];
    const float* rb = (const float*)d_in[2];
    const float* nw = (const float*)d_in[3];
    const float* nb = (const float*)d_in[4];
    const float* nu = (const float*)d_in[5];
    float* out = (float*)d_out;
    _Float16* wsB = (_Float16*)d_ws;
    (void)in_sizes; (void)n_in; (void)out_size; (void)ws_size;

    hipLaunchKernelGGL(conv_w_kernel, dim3(128), dim3(256), 0, stream, rw, nw, wsB);
    hipLaunchKernelGGL(gemm_router_kernel, dim3(M_TOTAL / BM), dim3(NT), 0, stream,
                       x, wsB, rb, nb, nu, out);
}

// Round 9
// 236.304 us; speedup vs baseline: 1.0902x; 1.0902x over previous
//
#include <hip/hip_runtime.h>
#include <math.h>

typedef __fp16   fp16x2  __attribute__((ext_vector_type(2)));
typedef _Float16 half8   __attribute__((ext_vector_type(8)));
typedef float    floatx4 __attribute__((ext_vector_type(4)));

#define M_TOTAL 16384
#define K_DIM   2048
#define BM      64
#define BK      32
#define NT      512
#define NCHUNK  (K_DIM / BK)   // 64

// halves offsets within one LDS buffer (BM=64)
// layout: [Ahi 2048][Alo 2048][Bhi 4096][Blo 4096] halves = 24576 B
#define A_HI  0
#define A_LO  2048
#define B_HI  4096
#define B_LO  8192
#define BUF_H 12288

__device__ __forceinline__ void gl_lds16(const _Float16* g, _Float16* l) {
    __builtin_amdgcn_global_load_lds((const __attribute__((address_space(1))) void*)g,
                                     (__attribute__((address_space(3))) void*)l, 16, 0, 0);
}

__device__ __forceinline__ void cvt_store(const float4 v, _Float16* hiP, _Float16* loP) {
    fp16x2 h01 = __builtin_amdgcn_cvt_pkrtz(v.x, v.y);
    fp16x2 h23 = __builtin_amdgcn_cvt_pkrtz(v.z, v.w);
    float r0 = (v.x - (float)h01.x) * 2048.0f;
    float r1 = (v.y - (float)h01.y) * 2048.0f;
    float r2 = (v.z - (float)h23.x) * 2048.0f;
    float r3 = (v.w - (float)h23.y) * 2048.0f;
    fp16x2 l01 = __builtin_amdgcn_cvt_pkrtz(r0, r1);
    fp16x2 l23 = __builtin_amdgcn_cvt_pkrtz(r2, r3);
    union { fp16x2 h[2]; uint2 u; } ph, pl;
    ph.h[0] = h01; ph.h[1] = h23;
    pl.h[0] = l01; pl.h[1] = l23;
    *(uint2*)hiP = ph.u;
    *(uint2*)loP = pl.u;
}

// Pre-convert W (router||noise, fp32 [128][2048]) into ws as hi/lo f16,
// granule-major per 32-k chunk: chunk c = 8192 halves:
//   hi: [(g*128 + col)*8 + j]  (g=0..3 k-granule, col=0..127, j=0..7)
//   lo: same at +4096 halves
__global__ __launch_bounds__(256) void conv_w_kernel(
    const float* __restrict__ rw, const float* __restrict__ nw,
    _Float16* __restrict__ wsB)
{
    const int u   = blockIdx.x * 256 + threadIdx.x;  // 0..32767
    const int col = u & 127;
    const int g   = (u >> 7) & 3;
    const int c   = u >> 9;
    const float* srcRow = (col < 64) ? (rw + (size_t)col * K_DIM)
                                     : (nw + (size_t)(col - 64) * K_DIM);
    const float* src = srcRow + c * BK + g * 8;
    const float4 v0 = *(const float4*)src;
    const float4 v1 = *(const float4*)(src + 4);
    union { fp16x2 h[4]; uint4 q; } ph, pl;
    ph.h[0] = __builtin_amdgcn_cvt_pkrtz(v0.x, v0.y);
    ph.h[1] = __builtin_amdgcn_cvt_pkrtz(v0.z, v0.w);
    ph.h[2] = __builtin_amdgcn_cvt_pkrtz(v1.x, v1.y);
    ph.h[3] = __builtin_amdgcn_cvt_pkrtz(v1.z, v1.w);
    pl.h[0] = __builtin_amdgcn_cvt_pkrtz((v0.x - (float)ph.h[0].x) * 2048.0f,
                                         (v0.y - (float)ph.h[0].y) * 2048.0f);
    pl.h[1] = __builtin_amdgcn_cvt_pkrtz((v0.z - (float)ph.h[1].x) * 2048.0f,
                                         (v0.w - (float)ph.h[1].y) * 2048.0f);
    pl.h[2] = __builtin_amdgcn_cvt_pkrtz((v1.x - (float)ph.h[2].x) * 2048.0f,
                                         (v1.y - (float)ph.h[2].y) * 2048.0f);
    pl.h[3] = __builtin_amdgcn_cvt_pkrtz((v1.z - (float)ph.h[3].x) * 2048.0f,
                                         (v1.w - (float)ph.h[3].y) * 2048.0f);
    const size_t base = (size_t)c * 8192 + ((size_t)g * 128 + col) * 8;
    *(uint4*)&wsB[base]        = ph.q;
    *(uint4*)&wsB[base + 4096] = pl.q;
}

// BM=64 / 512-thread version of the verified r0 template.
// grid = 256 = exactly 1 block/CU: per CU-chunk L1 traffic drops 40->24 KB
// (B's fixed 16 KB/chunk amortized over 64 rows instead of 32, and no
// second block on the CU re-reading the same B chunk).
// 8 waves as 2x4 tiles of 32x32; staging maps are r0's algebra at 64 rows.
__global__ __launch_bounds__(NT, 2) void gemm_router_kernel(
    const float* __restrict__ x,
    const _Float16* __restrict__ wsB,
    const float* __restrict__ router_b,
    const float* __restrict__ noise_b,
    const float* __restrict__ noise_u,
    float* __restrict__ out)
{
    __shared__ __align__(16) union {
        _Float16 S[2 * BUF_H];   // 49152 B
        struct { float Cs[64][132]; float p1[64]; float p2[64]; int i1[64]; int i2[64]; } e;
    } sm;

    const int t    = threadIdx.x;
    const int lane = t & 63;
    const int w    = t >> 6;           // 0..7
    const int rowBase = blockIdx.x * BM;

    // A staging map: thread -> (row r 0..63, k-quad q 0..7), fully coalesced
    const int r = t >> 3, q = t & 7;
    const float* pa = x + (size_t)(rowBase + r) * K_DIM + q * 4;
    const int aw = ((q >> 1) * 64 + r) * 8 + (q & 1) * 4;  // [g][row][8] halves

    // fragment map: wave w -> rows (w&1)*32..+31, cols (w>>1)*32..+31
    const int lr  = lane & 15;
    const int lg4 = lane >> 4;
    const int wr  = w & 1;
    const int wc  = w >> 1;
    const int mt0 = wr * 32;
    const int nt0 = wc * 32;

    floatx4 acch[2][2], accx[2][2];
    #pragma unroll
    for (int mi = 0; mi < 2; ++mi)
        #pragma unroll
        for (int ni = 0; ni < 2; ++ni) {
            acch[mi][ni] = (floatx4)0.0f;
            accx[mi][ni] = (floatx4)0.0f;
        }

    // prologue: stage B(0) (16 segments over 8 waves = 2/wave) + A(0)
    {
        #pragma unroll
        for (int i = 0; i < 2; ++i) {
            const int n = w * 2 + i;
            gl_lds16(wsB + n * 512 + lane * 8, &sm.S[B_HI + n * 512]);
        }
    }
    {
        const float4 a0 = *(const float4*)pa;
        cvt_store(a0, &sm.S[A_HI + aw], &sm.S[A_LO + aw]);
    }

    for (int c = 0; c < NCHUNK; ++c) {
        __syncthreads();  // B(c) arrived, A(c) staged, buf[(c+1)&1] reads done
        _Float16* buf  = sm.S + (c & 1) * BUF_H;
        _Float16* bufn = sm.S + ((c + 1) & 1) * BUF_H;

        float4 aReg;
        if (c + 1 < NCHUNK) {
            const _Float16* wcp = wsB + (size_t)(c + 1) * 8192;
            #pragma unroll
            for (int i = 0; i < 2; ++i) {
                const int n = w * 2 + i;
                gl_lds16(wcp + n * 512 + lane * 8, bufn + B_HI + n * 512);
            }
            aReg = *(const float4*)(pa + (c + 1) * BK);
        }

        half8 ah[2], al[2];
        #pragma unroll
        for (int mi = 0; mi < 2; ++mi) {
            const int ao = (lg4 * 64 + mt0 + mi * 16 + lr) * 8;
            ah[mi] = *(const half8*)&buf[A_HI + ao];
            al[mi] = *(const half8*)&buf[A_LO + ao];
        }
        half8 bh[2], bl[2];
        #pragma unroll
        for (int ni = 0; ni < 2; ++ni) {
            const int bo = (lg4 * 128 + nt0 + ni * 16 + lr) * 8;
            bh[ni] = *(const half8*)&buf[B_HI + bo];
            bl[ni] = *(const half8*)&buf[B_LO + bo];
        }
        #pragma unroll
        for (int mi = 0; mi < 2; ++mi)
            #pragma unroll
            for (int ni = 0; ni < 2; ++ni) {
                acch[mi][ni] = __builtin_amdgcn_mfma_f32_16x16x32_f16(ah[mi], bh[ni], acch[mi][ni], 0, 0, 0);
                accx[mi][ni] = __builtin_amdgcn_mfma_f32_16x16x32_f16(ah[mi], bl[ni], accx[mi][ni], 0, 0, 0);
                accx[mi][ni] = __builtin_amdgcn_mfma_f32_16x16x32_f16(al[mi], bh[ni], accx[mi][ni], 0, 0, 0);
            }
        if (c + 1 < NCHUNK)
            cvt_store(aReg, &bufn[A_HI + aw], &bufn[A_LO + aw]);
    }

    // Cs (33.8 KB) overlaps buf1 (chunk 63's read buffer): barrier first so
    // no wave is still ds_reading buf1 when Cs writes begin.
    __syncthreads();

    // ---- fused epilogue ----
    #pragma unroll
    for (int mi = 0; mi < 2; ++mi)
        #pragma unroll
        for (int ni = 0; ni < 2; ++ni) {
            const floatx4 v = acch[mi][ni] + accx[mi][ni] * (1.0f / 2048.0f);
            const int col = nt0 + ni * 16 + lr;
            #pragma unroll
            for (int reg = 0; reg < 4; ++reg)
                sm.e.Cs[mt0 + mi * 16 + lg4 * 4 + reg][col] = v[reg];
        }
    __syncthreads();

    // per-row top-2: 8 threads/row, 8 experts each, shuffle merge (512 = 64x8)
    {
        const int sr = t >> 3;          // row 0..63
        const int eg = (t & 7) * 8;     // expert base
        const int grow = rowBase + sr;
        const float* urow = noise_u + (size_t)grow * 64 + eg;
        const float4 u0 = *(const float4*)urow;
        const float4 u1 = *(const float4*)(urow + 4);
        const float uu[8] = {u0.x, u0.y, u0.z, u0.w, u1.x, u1.y, u1.z, u1.w};
        float v1 = -3.0e38f, v2 = -3.0e38f;
        int i1 = 0, i2 = 0;
        #pragma unroll
        for (int j = 0; j < 8; ++j) {
            const int e = eg + j;
            const float lg = sm.e.Cs[sr][e] + router_b[e];
            const float nz = sm.e.Cs[sr][64 + e] + noise_b[e];
            const float sp = fmaxf(nz, 0.0f) + log1pf(expf(-fabsf(nz)));
            const float nv = lg + sp * uu[j];
            if (nv > v1)      { v2 = v1; i2 = i1; v1 = nv; i1 = e; }
            else if (nv > v2) { v2 = nv; i2 = e; }
        }
        #pragma unroll
        for (int m = 1; m < 8; m <<= 1) {
            const float ov1 = __shfl_xor(v1, m, 64);
            const int   oi1 = __shfl_xor(i1, m, 64);
            const float ov2 = __shfl_xor(v2, m, 64);
            const int   oi2 = __shfl_xor(i2, m, 64);
            const bool takeO = (ov1 > v1) || (ov1 == v1 && oi1 < i1);
            const float t1v = takeO ? ov1 : v1;  const int t1i = takeO ? oi1 : i1;
            const float c2v = takeO ? v1 : ov1;  const int c2i = takeO ? i1 : oi1;
            const float c3v = takeO ? ov2 : v2;  const int c3i = takeO ? oi2 : i2;
            const bool k2 = (c3v > c2v) || (c3v == c2v && c3i < c2i);
            v1 = t1v; i1 = t1i;
            v2 = k2 ? c3v : c2v; i2 = k2 ? c3i : c2i;
        }
        if ((t & 7) == 0) {
            const float e2 = expf(v2 - v1);
            const float dn = 1.0f + e2;   // other 62 slots: exp(-1e30 - m) == 0
            sm.e.p1[sr] = 1.0f / dn;
            sm.e.p2[sr] = e2 / dn;
            sm.e.i1[sr] = i1;
            sm.e.i2[sr] = i2;
            float2 idx2;
            idx2.x = (float)i1;
            idx2.y = (float)i2;
            *(float2*)&out[(size_t)M_TOTAL * 64 + (size_t)grow * 2] = idx2;
        }
    }
    __syncthreads();

    // cooperative sparse-softmax write: 64 rows x 64 experts, 8 floats/thread
    {
        const int rr = t >> 3;
        const int e0 = (t & 7) * 8;
        const int g2 = rowBase + rr;
        const int j1 = sm.e.i1[rr], j2 = sm.e.i2[rr];
        const float q1 = sm.e.p1[rr], q2 = sm.e.p2[rr];
        float* orow = out + (size_t)g2 * 64;
        #pragma unroll
        for (int g = 0; g < 2; ++g) {
            const int b0 = e0 + g * 4;
            float4 v;
            v.x = (b0 + 0 == j1) ? q1 : (b0 + 0 == j2) ? q2 : 0.0f;
            v.y = (b0 + 1 == j1) ? q1 : (b0 + 1 == j2) ? q2 : 0.0f;
            v.z = (b0 + 2 == j1) ? q1 : (b0 + 2 == j2) ? q2 : 0.0f;
            v.w = (b0 + 3 == j1) ? q1 : (b0 + 3 == j2) ? q2 : 0.0f;
            *(float4*)&orow[b0] = v;
        }
    }
}

extern "C" void kernel_launch(void* const* d_in, const int* in_sizes, int n_in,
                              void* d_out, int out_size, void* d_ws, size_t ws_size,
                              hipStream_t stream) {
    const float* x  = (const float*)d_in[0];
    const float* rw = (const float*)d_in[1];
    const float* rb = (const float*)d_in[2];
    const float* nw = (const float*)d_in[3];
    const float* nb = (const float*)d_in[4];
    const float* nu = (const float*)d_in[5];
    float* out = (float*)d_out;
    _Float16* wsB = (_Float16*)d_ws;
    (void)in_sizes; (void)n_in; (void)out_size; (void)ws_size;

    hipLaunchKernelGGL(conv_w_kernel, dim3(128), dim3(256), 0, stream, rw, nw, wsB);
    hipLaunchKernelGGL(gemm_router_kernel, dim3(M_TOTAL / BM), dim3(NT), 0, stream,
                       x, wsB, rb, nb, nu, out);
}

// Round 10
// 232.295 us; speedup vs baseline: 1.1091x; 1.0173x over previous
//
#include <hip/hip_runtime.h>
#include <math.h>

typedef __fp16   fp16x2  __attribute__((ext_vector_type(2)));
typedef _Float16 half8   __attribute__((ext_vector_type(8)));
typedef float    floatx4 __attribute__((ext_vector_type(4)));

#define M_TOTAL 16384
#define K_DIM   2048
#define BM      32
#define BK      32
#define NT      256
#define NCHUNK  (K_DIM / BK)   // 64
#define NCH_H   32             // chunks per K-half

// halves offsets within one LDS buffer (BM=32, r0 layout)
#define A_HI  0
#define A_LO  1024
#define B_HI  2048
#define B_LO  6144
#define BUF_H 10240

#define WS_B_BYTES   (1u << 20)                 // wsB: 1 MiB
#define WS_PART_F    ((size_t)M_TOTAL * 128)    // one partial slot, floats
#define WS_NEED      (WS_B_BYTES + 2 * WS_PART_F * sizeof(float) + 65536)

__device__ __forceinline__ void gl_lds16(const _Float16* g, _Float16* l) {
    __builtin_amdgcn_global_load_lds((const __attribute__((address_space(1))) void*)g,
                                     (__attribute__((address_space(3))) void*)l, 16, 0, 0);
}

__device__ __forceinline__ void cvt_store(const float4 v, _Float16* hiP, _Float16* loP) {
    fp16x2 h01 = __builtin_amdgcn_cvt_pkrtz(v.x, v.y);
    fp16x2 h23 = __builtin_amdgcn_cvt_pkrtz(v.z, v.w);
    float r0 = (v.x - (float)h01.x) * 2048.0f;
    float r1 = (v.y - (float)h01.y) * 2048.0f;
    float r2 = (v.z - (float)h23.x) * 2048.0f;
    float r3 = (v.w - (float)h23.y) * 2048.0f;
    fp16x2 l01 = __builtin_amdgcn_cvt_pkrtz(r0, r1);
    fp16x2 l23 = __builtin_amdgcn_cvt_pkrtz(r2, r3);
    union { fp16x2 h[2]; uint2 u; } ph, pl;
    ph.h[0] = h01; ph.h[1] = h23;
    pl.h[0] = l01; pl.h[1] = l23;
    *(uint2*)hiP = ph.u;
    *(uint2*)loP = pl.u;
}

// Pre-convert W (router||noise, fp32 [128][2048]) into ws as hi/lo f16,
// granule-major per 32-k chunk (verified layout, unchanged).
__global__ __launch_bounds__(256) void conv_w_kernel(
    const float* __restrict__ rw, const float* __restrict__ nw,
    _Float16* __restrict__ wsB)
{
    const int u   = blockIdx.x * 256 + threadIdx.x;  // 0..32767
    const int col = u & 127;
    const int g   = (u >> 7) & 3;
    const int c   = u >> 9;
    const float* srcRow = (col < 64) ? (rw + (size_t)col * K_DIM)
                                     : (nw + (size_t)(col - 64) * K_DIM);
    const float* src = srcRow + c * BK + g * 8;
    const float4 v0 = *(const float4*)src;
    const float4 v1 = *(const float4*)(src + 4);
    union { fp16x2 h[4]; uint4 q; } ph, pl;
    ph.h[0] = __builtin_amdgcn_cvt_pkrtz(v0.x, v0.y);
    ph.h[1] = __builtin_amdgcn_cvt_pkrtz(v0.z, v0.w);
    ph.h[2] = __builtin_amdgcn_cvt_pkrtz(v1.x, v1.y);
    ph.h[3] = __builtin_amdgcn_cvt_pkrtz(v1.z, v1.w);
    pl.h[0] = __builtin_amdgcn_cvt_pkrtz((v0.x - (float)ph.h[0].x) * 2048.0f,
                                         (v0.y - (float)ph.h[0].y) * 2048.0f);
    pl.h[1] = __builtin_amdgcn_cvt_pkrtz((v0.z - (float)ph.h[1].x) * 2048.0f,
                                         (v0.w - (float)ph.h[1].y) * 2048.0f);
    pl.h[2] = __builtin_amdgcn_cvt_pkrtz((v1.x - (float)ph.h[2].x) * 2048.0f,
                                         (v1.y - (float)ph.h[2].y) * 2048.0f);
    pl.h[3] = __builtin_amdgcn_cvt_pkrtz((v1.z - (float)ph.h[3].x) * 2048.0f,
                                         (v1.w - (float)ph.h[3].y) * 2048.0f);
    const size_t base = (size_t)c * 8192 + ((size_t)g * 128 + col) * 8;
    *(uint4*)&wsB[base]        = ph.q;
    *(uint4*)&wsB[base + 4096] = pl.q;
}

// K-split stage 1: r0's verified 90-us loop body, but each block owns only
// HALF of K (32 chunks). Grid 1024 = 512 row-tiles x 2 K-halves:
//   tile = bid & 511, kh = bid >> 9  -> block b and b+512 share rows but read
//   DISJOINT x bytes (different K-columns): zero traffic amplification,
//   double the independent barrier groups per CU (4 blocks/CU: LDS 40KBx4 =
//   160KB exact, VGPR ~52). Partial C (fp32) written to workspace.
__global__ __launch_bounds__(NT, 4) void gemm_partial_kernel(
    const float* __restrict__ x,
    const _Float16* __restrict__ wsB,
    float* __restrict__ part)
{
    __shared__ __align__(16) _Float16 S[2 * BUF_H];   // 40960 B

    const int t    = threadIdx.x;
    const int lane = t & 63;
    const int w    = t >> 6;
    const int tile = blockIdx.x & 511;
    const int kh   = blockIdx.x >> 9;
    const int rowBase = tile * BM;

    // A staging map (r0): thread -> (row r, k-quad q), fully coalesced
    const int r = t >> 3, q = t & 7;
    const float* pa = x + (size_t)(rowBase + r) * K_DIM + kh * (NCH_H * BK) + q * 4;
    const int aw = ((q >> 1) * 32 + r) * 8 + (q & 1) * 4;

    // fragment map (r0): wave w -> rows mt0..+16, cols nt0..+64
    const int lr  = lane & 15;
    const int lg4 = lane >> 4;
    const int mt0 = (w & 1) * 16;
    const int nt0 = (w >> 1) * 64;
    const int aOff = (lg4 * 32 + mt0 + lr) * 8;

    const _Float16* wsBase = wsB + (size_t)kh * NCH_H * 8192;

    floatx4 acch[4], accx[4];
    #pragma unroll
    for (int ni = 0; ni < 4; ++ni) { acch[ni] = (floatx4)0.0f; accx[ni] = (floatx4)0.0f; }

    // prologue: stage B(first) + A(first)
    {
        #pragma unroll
        for (int i = 0; i < 4; ++i) {
            const int n = w * 4 + i;
            gl_lds16(wsBase + n * 512 + lane * 8, &S[B_HI + n * 512]);
        }
    }
    {
        const float4 a0 = *(const float4*)pa;
        cvt_store(a0, &S[A_HI + aw], &S[A_LO + aw]);
    }

    for (int c = 0; c < NCH_H; ++c) {
        __syncthreads();  // B(c) arrived, A(c) staged, buf[(c+1)&1] reads done
        _Float16* buf  = S + (c & 1) * BUF_H;
        _Float16* bufn = S + ((c + 1) & 1) * BUF_H;

        float4 aReg;
        if (c + 1 < NCH_H) {
            const _Float16* wc = wsBase + (size_t)(c + 1) * 8192;
            #pragma unroll
            for (int i = 0; i < 4; ++i) {
                const int n = w * 4 + i;
                gl_lds16(wc + n * 512 + lane * 8, bufn + B_HI + n * 512);
            }
            aReg = *(const float4*)(pa + (c + 1) * BK);
        }

        const half8 ah = *(const half8*)&buf[A_HI + aOff];
        const half8 al = *(const half8*)&buf[A_LO + aOff];
        half8 bh[4], bl[4];
        #pragma unroll
        for (int ni = 0; ni < 4; ++ni) {
            const int bo = (lg4 * 128 + nt0 + ni * 16 + lr) * 8;
            bh[ni] = *(const half8*)&buf[B_HI + bo];
            bl[ni] = *(const half8*)&buf[B_LO + bo];
        }
        #pragma unroll
        for (int ni = 0; ni < 4; ++ni) {
            acch[ni] = __builtin_amdgcn_mfma_f32_16x16x32_f16(ah, bh[ni], acch[ni], 0, 0, 0);
            accx[ni] = __builtin_amdgcn_mfma_f32_16x16x32_f16(ah, bl[ni], accx[ni], 0, 0, 0);
            accx[ni] = __builtin_amdgcn_mfma_f32_16x16x32_f16(al, bh[ni], accx[ni], 0, 0, 0);
        }
        if (c + 1 < NCH_H)
            cvt_store(aReg, &bufn[A_HI + aw], &bufn[A_LO + aw]);
    }

    // write fp32 partial: part[kh][row][col]
    float* myP = part + (size_t)kh * WS_PART_F + (size_t)rowBase * 128;
    #pragma unroll
    for (int ni = 0; ni < 4; ++ni) {
        const floatx4 v = acch[ni] + accx[ni] * (1.0f / 2048.0f);
        const int col = nt0 + ni * 16 + lr;
        #pragma unroll
        for (int reg = 0; reg < 4; ++reg)
            myP[(size_t)(mt0 + lg4 * 4 + reg) * 128 + col] = v[reg];
    }
}

// K-split stage 2: sum the two partials, add biases, softplus-noise, top-2,
// sparse softmax, write out. 512 blocks x 32 rows; logic identical to the
// verified fused epilogue, Cs sourced from global partials.
__global__ __launch_bounds__(256) void router_epilogue_kernel(
    const float* __restrict__ part,
    const float* __restrict__ router_b,
    const float* __restrict__ noise_b,
    const float* __restrict__ noise_u,
    float* __restrict__ out)
{
    __shared__ struct { float p1[32]; float p2[32]; int i1[32]; int i2[32]; } sm;

    const int t  = threadIdx.x;
    const int sr = t >> 3;          // row 0..31
    const int tg = t & 7;
    const int eg = tg * 8;          // expert base
    const int grow = blockIdx.x * 32 + sr;

    {
        const float* q0 = part + (size_t)grow * 128;
        const float* q1 = part + WS_PART_F + (size_t)grow * 128;
        const float4 l0a = *(const float4*)(q0 + eg);
        const float4 l0b = *(const float4*)(q0 + eg + 4);
        const float4 l1a = *(const float4*)(q1 + eg);
        const float4 l1b = *(const float4*)(q1 + eg + 4);
        const float4 n0a = *(const float4*)(q0 + 64 + eg);
        const float4 n0b = *(const float4*)(q0 + 64 + eg + 4);
        const float4 n1a = *(const float4*)(q1 + 64 + eg);
        const float4 n1b = *(const float4*)(q1 + 64 + eg + 4);
        const float4 rba = *(const float4*)(router_b + eg);
        const float4 rbb = *(const float4*)(router_b + eg + 4);
        const float4 nba = *(const float4*)(noise_b + eg);
        const float4 nbb = *(const float4*)(noise_b + eg + 4);
        const float* urow = noise_u + (size_t)grow * 64 + eg;
        const float4 u0 = *(const float4*)urow;
        const float4 u1 = *(const float4*)(urow + 4);

        const float lg_[8] = {l0a.x + l1a.x + rba.x, l0a.y + l1a.y + rba.y,
                              l0a.z + l1a.z + rba.z, l0a.w + l1a.w + rba.w,
                              l0b.x + l1b.x + rbb.x, l0b.y + l1b.y + rbb.y,
                              l0b.z + l1b.z + rbb.z, l0b.w + l1b.w + rbb.w};
        const float nz_[8] = {n0a.x + n1a.x + nba.x, n0a.y + n1a.y + nba.y,
                              n0a.z + n1a.z + nba.z, n0a.w + n1a.w + nba.w,
                              n0b.x + n1b.x + nbb.x, n0b.y + n1b.y + nbb.y,
                              n0b.z + n1b.z + nbb.z, n0b.w + n1b.w + nbb.w};
        const float uu[8] = {u0.x, u0.y, u0.z, u0.w, u1.x, u1.y, u1.z, u1.w};

        float v1 = -3.0e38f, v2 = -3.0e38f;
        int i1 = 0, i2 = 0;
        #pragma unroll
        for (int j = 0; j < 8; ++j) {
            const int e = eg + j;
            const float sp = fmaxf(nz_[j], 0.0f) + log1pf(expf(-fabsf(nz_[j])));
            const float nv = lg_[j] + sp * uu[j];
            if (nv > v1)      { v2 = v1; i2 = i1; v1 = nv; i1 = e; }
            else if (nv > v2) { v2 = nv; i2 = e; }
        }
        #pragma unroll
        for (int m = 1; m < 8; m <<= 1) {
            const float ov1 = __shfl_xor(v1, m, 64);
            const int   oi1 = __shfl_xor(i1, m, 64);
            const float ov2 = __shfl_xor(v2, m, 64);
            const int   oi2 = __shfl_xor(i2, m, 64);
            const bool takeO = (ov1 > v1) || (ov1 == v1 && oi1 < i1);
            const float t1v = takeO ? ov1 : v1;  const int t1i = takeO ? oi1 : i1;
            const float c2v = takeO ? v1 : ov1;  const int c2i = takeO ? i1 : oi1;
            const float c3v = takeO ? ov2 : v2;  const int c3i = takeO ? oi2 : i2;
            const bool k2 = (c3v > c2v) || (c3v == c2v && c3i < c2i);
            v1 = t1v; i1 = t1i;
            v2 = k2 ? c3v : c2v; i2 = k2 ? c3i : c2i;
        }
        if (tg == 0) {
            const float e2 = expf(v2 - v1);
            const float dn = 1.0f + e2;
            sm.p1[sr] = 1.0f / dn;
            sm.p2[sr] = e2 / dn;
            sm.i1[sr] = i1;
            sm.i2[sr] = i2;
            float2 idx2;
            idx2.x = (float)i1;
            idx2.y = (float)i2;
            *(float2*)&out[(size_t)M_TOTAL * 64 + (size_t)grow * 2] = idx2;
        }
    }
    __syncthreads();

    {
        const int rr = t >> 3;
        const int e0 = (t & 7) * 8;
        const int g2 = blockIdx.x * 32 + rr;
        const int j1 = sm.i1[rr], j2 = sm.i2[rr];
        const float q1 = sm.p1[rr], q2 = sm.p2[rr];
        float* orow = out + (size_t)g2 * 64;
        #pragma unroll
        for (int g = 0; g < 2; ++g) {
            const int b0 = e0 + g * 4;
            float4 v;
            v.x = (b0 + 0 == j1) ? q1 : (b0 + 0 == j2) ? q2 : 0.0f;
            v.y = (b0 + 1 == j1) ? q1 : (b0 + 1 == j2) ? q2 : 0.0f;
            v.z = (b0 + 2 == j1) ? q1 : (b0 + 2 == j2) ? q2 : 0.0f;
            v.w = (b0 + 3 == j1) ? q1 : (b0 + 3 == j2) ? q2 : 0.0f;
            *(float4*)&orow[b0] = v;
        }
    }
}

// ---- fallback: the verified r0 fused kernel (used if ws too small) ----
__global__ __launch_bounds__(NT, 2) void gemm_router_fused(
    const float* __restrict__ x,
    const _Float16* __restrict__ wsB,
    const float* __restrict__ router_b,
    const float* __restrict__ noise_b,
    const float* __restrict__ noise_u,
    float* __restrict__ out)
{
    __shared__ __align__(16) union {
        _Float16 S[2 * BUF_H];
        struct { float Cs[32][132]; float p1[32]; float p2[32]; int i1[32]; int i2[32]; } e;
    } sm;

    const int t    = threadIdx.x;
    const int lane = t & 63;
    const int w    = t >> 6;
    const int rowBase = blockIdx.x * BM;

    const int r = t >> 3, q = t & 7;
    const float* pa = x + (size_t)(rowBase + r) * K_DIM + q * 4;
    const int aw = ((q >> 1) * 32 + r) * 8 + (q & 1) * 4;

    const int lr  = lane & 15;
    const int lg4 = lane >> 4;
    const int mt0 = (w & 1) * 16;
    const int nt0 = (w >> 1) * 64;
    const int aOff = (lg4 * 32 + mt0 + lr) * 8;

    floatx4 acch[4], accx[4];
    #pragma unroll
    for (int ni = 0; ni < 4; ++ni) { acch[ni] = (floatx4)0.0f; accx[ni] = (floatx4)0.0f; }

    {
        #pragma unroll
        for (int i = 0; i < 4; ++i) {
            const int n = w * 4 + i;
            gl_lds16(wsB + n * 512 + lane * 8, &sm.S[B_HI + n * 512]);
        }
    }
    {
        const float4 a0 = *(const float4*)pa;
        cvt_store(a0, &sm.S[A_HI + aw], &sm.S[A_LO + aw]);
    }

    for (int c = 0; c < NCHUNK; ++c) {
        __syncthreads();
        _Float16* buf  = sm.S + (c & 1) * BUF_H;
        _Float16* bufn = sm.S + ((c + 1) & 1) * BUF_H;

        float4 aReg;
        if (c + 1 < NCHUNK) {
            const _Float16* wc = wsB + (size_t)(c + 1) * 8192;
            #pragma unroll
            for (int i = 0; i < 4; ++i) {
                const int n = w * 4 + i;
                gl_lds16(wc + n * 512 + lane * 8, bufn + B_HI + n * 512);
            }
            aReg = *(const float4*)(pa + (c + 1) * BK);
        }

        const half8 ah = *(const half8*)&buf[A_HI + aOff];
        const half8 al = *(const half8*)&buf[A_LO + aOff];
        half8 bh[4], bl[4];
        #pragma unroll
        for (int ni = 0; ni < 4; ++ni) {
            const int bo = (lg4 * 128 + nt0 + ni * 16 + lr) * 8;
            bh[ni] = *(const half8*)&buf[B_HI + bo];
            bl[ni] = *(const half8*)&buf[B_LO + bo];
        }
        #pragma unroll
        for (int ni = 0; ni < 4; ++ni) {
            acch[ni] = __builtin_amdgcn_mfma_f32_16x16x32_f16(ah, bh[ni], acch[ni], 0, 0, 0);
            accx[ni] = __builtin_amdgcn_mfma_f32_16x16x32_f16(ah, bl[ni], accx[ni], 0, 0, 0);
            accx[ni] = __builtin_amdgcn_mfma_f32_16x16x32_f16(al, bh[ni], accx[ni], 0, 0, 0);
        }
        if (c + 1 < NCHUNK)
            cvt_store(aReg, &bufn[A_HI + aw], &bufn[A_LO + aw]);
    }

    #pragma unroll
    for (int ni = 0; ni < 4; ++ni) {
        const floatx4 v = acch[ni] + accx[ni] * (1.0f / 2048.0f);
        const int col = nt0 + ni * 16 + lr;
        #pragma unroll
        for (int reg = 0; reg < 4; ++reg)
            sm.e.Cs[mt0 + lg4 * 4 + reg][col] = v[reg];
    }
    __syncthreads();

    {
        const int sr = t >> 3;
        const int eg = (t & 7) * 8;
        const int grow = rowBase + sr;
        const float* urow = noise_u + (size_t)grow * 64 + eg;
        const float4 u0 = *(const float4*)urow;
        const float4 u1 = *(const float4*)(urow + 4);
        const float uu[8] = {u0.x, u0.y, u0.z, u0.w, u1.x, u1.y, u1.z, u1.w};
        float v1 = -3.0e38f, v2 = -3.0e38f;
        int i1 = 0, i2 = 0;
        #pragma unroll
        for (int j = 0; j < 8; ++j) {
            const int e = eg + j;
            const float lg = sm.e.Cs[sr][e] + router_b[e];
            const float nz = sm.e.Cs[sr][64 + e] + noise_b[e];
            const float sp = fmaxf(nz, 0.0f) + log1pf(expf(-fabsf(nz)));
            const float nv = lg + sp * uu[j];
            if (nv > v1)      { v2 = v1; i2 = i1; v1 = nv; i1 = e; }
            else if (nv > v2) { v2 = nv; i2 = e; }
        }
        #pragma unroll
        for (int m = 1; m < 8; m <<= 1) {
            const float ov1 = __shfl_xor(v1, m, 64);
            const int   oi1 = __shfl_xor(i1, m, 64);
            const float ov2 = __shfl_xor(v2, m, 64);
            const int   oi2 = __shfl_xor(i2, m, 64);
            const bool takeO = (ov1 > v1) || (ov1 == v1 && oi1 < i1);
            const float t1v = takeO ? ov1 : v1;  const int t1i = takeO ? oi1 : i1;
            const float c2v = takeO ? v1 : ov1;  const int c2i = takeO ? i1 : oi1;
            const float c3v = takeO ? ov2 : v2;  const int c3i = takeO ? oi2 : i2;
            const bool k2 = (c3v > c2v) || (c3v == c2v && c3i < c2i);
            v1 = t1v; i1 = t1i;
            v2 = k2 ? c3v : c2v; i2 = k2 ? c3i : c2i;
        }
        if ((t & 7) == 0) {
            const float e2 = expf(v2 - v1);
            const float dn = 1.0f + e2;
            sm.e.p1[sr] = 1.0f / dn;
            sm.e.p2[sr] = e2 / dn;
            sm.e.i1[sr] = i1;
            sm.e.i2[sr] = i2;
            float2 idx2;
            idx2.x = (float)i1;
            idx2.y = (float)i2;
            *(float2*)&out[(size_t)M_TOTAL * 64 + (size_t)grow * 2] = idx2;
        }
    }
    __syncthreads();

    {
        const int rr = t >> 3;
        const int e0 = (t & 7) * 8;
        const int g2 = rowBase + rr;
        const int j1 = sm.e.i1[rr], j2 = sm.e.i2[rr];
        const float q1 = sm.e.p1[rr], q2 = sm.e.p2[rr];
        float* orow = out + (size_t)g2 * 64;
        #pragma unroll
        for (int g = 0; g < 2; ++g) {
            const int b0 = e0 + g * 4;
            float4 v;
            v.x = (b0 + 0 == j1) ? q1 : (b0 + 0 == j2) ? q2 : 0.0f;
            v.y = (b0 + 1 == j1) ? q1 : (b0 + 1 == j2) ? q2 : 0.0f;
            v.z = (b0 + 2 == j1) ? q1 : (b0 + 2 == j2) ? q2 : 0.0f;
            v.w = (b0 + 3 == j1) ? q1 : (b0 + 3 == j2) ? q2 : 0.0f;
            *(float4*)&orow[b0] = v;
        }
    }
}

extern "C" void kernel_launch(void* const* d_in, const int* in_sizes, int n_in,
                              void* d_out, int out_size, void* d_ws, size_t ws_size,
                              hipStream_t stream) {
    const float* x  = (const float*)d_in[0];
    const float* rw = (const float*)d_in[1];
    const float* rb = (const float*)d_in[2];
    const float* nw = (const float*)d_in[3];
    const float* nb = (const float*)d_in[4];
    const float* nu = (const float*)d_in[5];
    float* out = (float*)d_out;
    _Float16* wsB = (_Float16*)d_ws;
    (void)in_sizes; (void)n_in; (void)out_size;

    hipLaunchKernelGGL(conv_w_kernel, dim3(128), dim3(256), 0, stream, rw, nw, wsB);

    if (ws_size >= WS_NEED) {
        float* part = (float*)((char*)d_ws + WS_B_BYTES);
        hipLaunchKernelGGL(gemm_partial_kernel, dim3(1024), dim3(NT), 0, stream,
                           x, wsB, part);
        hipLaunchKernelGGL(router_epilogue_kernel, dim3(512), dim3(256), 0, stream,
                           part, rb, nb, nu, out);
    } else {
        hipLaunchKernelGGL(gemm_router_fused, dim3(M_TOTAL / BM), dim3(NT), 0, stream,
                           x, wsB, rb, nb, nu, out);
    }
}